// Round 2
// baseline (388.711 us; speedup 1.0000x reference)
//
#include <hip/hip_runtime.h>
#include <math.h>

// SteerableKernel: rotate [O,I,9,9] fp32 weights by G angles via bilinear
// grid_sample (zeros padding, align_corners=False).
// out[(g*C + c)*81 + p] , c = o*I+i, p = y*9+x, C = O*I.
//
// Table (d_ws), per (g,p): two source-row base indices b0,b1 and four weights
// W00,W01,W10,W11 with ALL edge/validity handling folded in, chosen so
//   val = img[b0]*W00 + img[b0+1]*W01 + img[b1]*W10 + img[b1+1]*W11
// and b+1 never exceeds 80 (xb clamped to [0,7]).  Pair reads -> ds_read2_b32.
//
// Main kernel: block stages NC=64 channels in LDS (20.7 KB -> 7 blocks/CU),
// threads t<243 own (c_local=t/81, p=t%81); per (g, cc) each thread reads its
// 2 LDS pairs and stores one dword at base + cc*243 + t (block-consecutive,
// coalesced).  Pure integer indexing into __shared__ keeps loads on the DS
// pipe (R0 suspect: char* addrspace cast -> flat_load).

#define KS   9
#define NPIX 81
#define NC   64
#define BLOCK 256
#define NENT_MAX 648   // G*NPIX for G=8

__global__ void st_make_table(float4* __restrict__ tw, int2* __restrict__ tb, int G) {
    int i = blockIdx.x * blockDim.x + threadIdx.x;
    if (i >= G * NPIX) return;
    int g = i / NPIX, p = i - g * NPIX;
    int py = p / KS, px = p - py * KS;
    double th = 6.283185307179586 * (double)g / (double)G;
    double ct = cos(th), st = sin(th);
    double lx = ((double)px + 0.5) * (2.0 / KS) - 1.0;   // x (width)
    double ly = ((double)py + 0.5) * (2.0 / KS) - 1.0;   // y (height)
    double gx = ct * lx - st * ly;
    double gy = st * lx + ct * ly;
    double ix = ((gx + 1.0) * KS - 1.0) * 0.5;
    double iy = ((gy + 1.0) * KS - 1.0) * 0.5;
    double fx = ix - floor(ix), fy = iy - floor(iy);
    int xi0 = (int)floor(ix), yi0 = (int)floor(iy);
    // x pair: base xb in [0,7]; weights permuted so (xb, xb+1) carries the
    // contributions of (xi0, xi0+1) with validity folded in.
    int xb = xi0 < 0 ? 0 : (xi0 > KS - 2 ? KS - 2 : xi0);
    double wa = (xi0 >= 0 && xi0 < KS) ? (1.0 - fx) : 0.0;
    double wb = (xi0 + 1 >= 0 && xi0 + 1 < KS) ? fx : 0.0;
    double w0 = (xi0 == xb ? wa : 0.0) + (xi0 + 1 == xb ? wb : 0.0);
    double w1 = (xi0 == xb + 1 ? wa : 0.0) + (xi0 + 1 == xb + 1 ? wb : 0.0);
    float W[2][2]; int B[2];
#pragma unroll
    for (int r = 0; r < 2; ++r) {
        int y = yi0 + r;
        double wy = (r ? fy : 1.0 - fy) * ((y >= 0 && y < KS) ? 1.0 : 0.0);
        int yc = y < 0 ? 0 : (y > KS - 1 ? KS - 1 : y);
        W[r][0] = (float)(wy * w0);
        W[r][1] = (float)(wy * w1);
        B[r] = yc * KS + xb;                 // max 8*9+7 = 79, so B+1 <= 80
    }
    tw[i] = make_float4(W[0][0], W[0][1], W[1][0], W[1][1]);
    tb[i] = make_int2(B[0], B[1]);
}

template <int GO>   // GO>0: compile-time group order (unrolled); GO==0: runtime
__global__ __launch_bounds__(BLOCK) void st_rotate(
        const float* __restrict__ in, const float4* __restrict__ tw,
        const int2* __restrict__ tb, float* __restrict__ out, int C, int Grt) {
    __shared__ float lin[NC * NPIX];        // 5184 floats = 20736 B
    const int t = threadIdx.x;
    const int c0 = blockIdx.x * NC;

    // Stage NC channels, coalesced float4 (c0*81*4 = 20736*blk -> 16B aligned).
    {
        const float4* src = (const float4*)(in + (size_t)c0 * NPIX);
        float4* dst = (float4*)lin;
#pragma unroll
        for (int j = 0; j < (NC * NPIX / 4 + BLOCK - 1) / BLOCK; ++j) {
            int idx = j * BLOCK + t;
            if (idx < NC * NPIX / 4) dst[idx] = src[idx];
        }
    }
    __syncthreads();

    if (t >= 3 * NPIX) return;              // 243 active threads
    const int c_local = t / NPIX;           // 0..2
    const int p = t - c_local * NPIX;
    const int G = GO > 0 ? GO : Grt;

#pragma unroll
    for (int g = 0; g < G; ++g) {
        const float4 w = tw[g * NPIX + p];
        const int2  b = tb[g * NPIX + p];
        const int i0 = c_local * NPIX + b.x;
        const int i1 = c_local * NPIX + b.y;
        float* og = out + ((size_t)g * C + c0) * NPIX + t;
        // channels c = 3*cc + c_local; cc=0..20 valid for all c_local (c<=62)
#pragma unroll
        for (int cc = 0; cc < 21; ++cc) {
            const int cb = cc * (3 * NPIX);
            float v = lin[cb + i0] * w.x + lin[cb + i0 + 1] * w.y
                    + lin[cb + i1] * w.z + lin[cb + i1 + 1] * w.w;
            og[cc * (3 * NPIX)] = v;
        }
        if (c_local == 0) {                 // tail: c = 63
            const int cb = 21 * (3 * NPIX);
            og[cb] = lin[cb + i0] * w.x + lin[cb + i0 + 1] * w.y
                   + lin[cb + i1] * w.z + lin[cb + i1 + 1] * w.w;
        }
    }
}

extern "C" void kernel_launch(void* const* d_in, const int* in_sizes, int n_in,
                              void* d_out, int out_size, void* d_ws, size_t ws_size,
                              hipStream_t stream) {
    const float* in = (const float*)d_in[0];
    float* out = (float*)d_out;
    const int C = in_sizes[0] / NPIX;          // 131072
    const int G = out_size / in_sizes[0];      // 8
    float4* tw = (float4*)d_ws;                        // 648 * 16 B
    int2*   tb = (int2*)((char*)d_ws + NENT_MAX * 16); // 648 * 8 B
    const int ents = G * NPIX;
    st_make_table<<<(ents + 255) / 256, 256, 0, stream>>>(tw, tb, G);
    if (G == 8)
        st_rotate<8><<<C / NC, BLOCK, 0, stream>>>(in, tw, tb, out, C, G);
    else
        st_rotate<0><<<C / NC, BLOCK, 0, stream>>>(in, tw, tb, out, C, G);
}